// Round 5
// baseline (84179.517 us; speedup 1.0000x reference)
//
#include <hip/hip_runtime.h>
#include <hip/hip_bf16.h>

#define HD 2048      // hidden size
#define TT 8192      // time steps
#define RPB 8        // rows per block
#define NBLK 256     // blocks (= H / RPB)
#define NTHR 256     // threads per block
#define SENTU 0xAAAAAAAAu

__device__ __forceinline__ float fix_sent(float v) {
    // avoid emitting the sentinel bit pattern as real data (prob ~0, but free)
    return (__float_as_uint(v) == SENTU) ? __uint_as_float(0xAAAAAABAu) : v;
}

__device__ __forceinline__ void slot_store(float* p, float v) {
    __hip_atomic_store(p, fix_sent(v), __ATOMIC_RELAXED, __HIP_MEMORY_SCOPE_AGENT);
}

__device__ __forceinline__ float slot_load(const float* p) {
    return __hip_atomic_load((float*)p, __ATOMIC_RELAXED, __HIP_MEMORY_SCOPE_AGENT);
}

// Poll the 8 slot words this thread needs. Doubly bounded (per-step cap +
// global budget): worst case is a fast wrong answer, never a wedge.
// Polling the data itself (vs a flag) needs no release/acquire ordering:
// each word is independently valid the moment it reads non-sentinel.
__device__ __forceinline__ void poll8(const float* src, float* stash, long& gbudget) {
    #pragma unroll
    for (int j = 0; j < 8; ++j) stash[j] = __uint_as_float(SENTU);
    int passes = 512;                        // ~64 us cap; legit lag ~1-2 us
    for (;;) {
        bool ok = true;
        #pragma unroll
        for (int j = 0; j < 8; ++j) {
            if (__float_as_uint(stash[j]) == SENTU) {
                stash[j] = slot_load(src + j);
                if (__float_as_uint(stash[j]) == SENTU) ok = false;
            }
        }
        if (ok) return;
        if (--passes < 0 || --gbudget < 0) {
            #pragma unroll
            for (int j = 0; j < 8; ++j)
                if (__float_as_uint(stash[j]) == SENTU) stash[j] = 0.f;
            return;
        }
        __builtin_amdgcn_s_sleep(2);         // ~128 cy backoff, cuts LLC poll slam
    }
}

// ---------------------------------------------------------------------------
// Layer 0: h_{s+1} = tanh(x[s]*Wih + b_ih + b_hh + Whh @ h_s)
// 256 blocks x 256 threads, block b owns rows [8b, 8b+8).
// thread (r = tid>>5, l = tid&31) covers k in [l*64, l*64+64) of row 8b+r.
// Weights live in 64 VGPRs per thread; read from HBM exactly once.
// Sync is pure data-flow polling on once-written slot words
// (sentinel = 0xAAAAAAAA from our own memset).
// ---------------------------------------------------------------------------
__global__ __launch_bounds__(NTHR, 1)
void rnn_l0(const float* __restrict__ x,
            const float* __restrict__ h_init,
            const float* __restrict__ Wih,
            const float* __restrict__ Whh,
            const float* __restrict__ bih,
            const float* __restrict__ bhh,
            float* __restrict__ slots,     // (TT+1) x HD
            float* __restrict__ outp)      // 2048 (final h of layer 0)
{
    __shared__ float xs[TT];       // 32 KB: whole input sequence
    __shared__ float hb[2][HD];    // 16 KB: double-buffered h stage

    const int tid = threadIdx.x;
    const int bid = blockIdx.x;
    const int r   = tid >> 5;
    const int l   = tid & 31;
    const int row = bid * RPB + r;

    for (int i = tid; i < TT; i += NTHR) xs[i] = x[i];

    // weight slice -> registers (coalesced: wave reads 2 full rows contiguously)
    float w[64];
    {
        const float4* wr = reinterpret_cast<const float4*>(Whh + (size_t)row * HD + l * 64);
        #pragma unroll
        for (int j = 0; j < 16; ++j) {
            float4 v = wr[j];
            w[4*j+0] = v.x; w[4*j+1] = v.y; w[4*j+2] = v.z; w[4*j+3] = v.w;
        }
    }
    const float wx   = Wih[row];
    const float bias = bih[row] + bhh[row];

    // publish initial h (slot 0), own rows only
    if (l == 0) slot_store(&slots[row], h_init[row]);

    // LDS xor-swizzle: word idx -> idx ^ (((idx>>6)&7)<<2). Breaks the
    // 32-way bank conflict of stride-64-word b128 reads down to 4-way.
    // Swizzled offsets stay multiples of 4 words (16B-aligned) and < 2048.
    const int swz_w = ((tid >> 3) & 7) << 2;   // (idx>>6)&7 for idx in [8*tid, 8*tid+8)
    const int swz_r = (l & 7) << 2;            // (idx>>6)&7 for idx in [l*64, l*64+64)

    float lastv = 0.f;
    long  gbudget = 1L << 21;   // ~25x total legit wait; worst case ~0.25 s

    for (int s = 0; s < TT; ++s) {
        float stash[8];
        poll8(slots + (size_t)s * HD + tid * 8, stash, gbudget);

        float* hbuf = hb[s & 1];
        {
            const int base = tid * 8;
            float4 v0 = make_float4(stash[0], stash[1], stash[2], stash[3]);
            float4 v1 = make_float4(stash[4], stash[5], stash[6], stash[7]);
            *reinterpret_cast<float4*>(&hbuf[(base    ) ^ swz_w]) = v0;
            *reinterpret_cast<float4*>(&hbuf[(base + 4) ^ swz_w]) = v1;
        }
        __syncthreads();

        float acc = 0.f;
        const int hbase = l * 64;
        #pragma unroll
        for (int q = 0; q < 16; ++q) {
            float4 hv = *reinterpret_cast<const float4*>(&hbuf[(hbase + 4*q) ^ swz_r]);
            acc = fmaf(w[4*q+0], hv.x, acc);
            acc = fmaf(w[4*q+1], hv.y, acc);
            acc = fmaf(w[4*q+2], hv.z, acc);
            acc = fmaf(w[4*q+3], hv.w, acc);
        }
        #pragma unroll
        for (int m = 1; m < 32; m <<= 1) acc += __shfl_xor(acc, m);

        float val = tanhf(acc + bias + xs[s] * wx);
        lastv = val;
        if (l == 0) slot_store(&slots[(size_t)(s + 1) * HD + row], val);
        // no trailing barrier needed: next step writes the other hb buffer,
        // and the per-step __syncthreads orders buffer reuse two steps apart.
    }
    if (l == 0) outp[row] = lastv;
}

// ---------------------------------------------------------------------------
// Layer 1: h_{s+1} = tanh(Wih @ h0_{s+1} + b_ih + b_hh + Whh @ h_s)
// h0 history is complete (previous kernel on same stream) -> plain cached loads.
// ---------------------------------------------------------------------------
__global__ __launch_bounds__(NTHR, 1)
void rnn_l1(const float* __restrict__ h_init,
            const float* __restrict__ Wih,      // HxH
            const float* __restrict__ Whh,      // HxH
            const float* __restrict__ bih,
            const float* __restrict__ bhh,
            const float* __restrict__ h0slots,  // (TT+1) x HD, read-only
            float* __restrict__ slots,          // (TT+1) x HD for layer 1
            float* __restrict__ outp)           // d_out + 2048
{
    __shared__ float hb1[2][HD];
    __shared__ float hb0[2][HD];

    const int tid = threadIdx.x;
    const int bid = blockIdx.x;
    const int r   = tid >> 5;
    const int l   = tid & 31;
    const int row = bid * RPB + r;

    float wh[64], wi[64];
    {
        const float4* a = reinterpret_cast<const float4*>(Whh + (size_t)row * HD + l * 64);
        const float4* b = reinterpret_cast<const float4*>(Wih + (size_t)row * HD + l * 64);
        #pragma unroll
        for (int j = 0; j < 16; ++j) {
            float4 v = a[j];
            wh[4*j+0] = v.x; wh[4*j+1] = v.y; wh[4*j+2] = v.z; wh[4*j+3] = v.w;
            float4 u = b[j];
            wi[4*j+0] = u.x; wi[4*j+1] = u.y; wi[4*j+2] = u.z; wi[4*j+3] = u.w;
        }
    }
    const float bias = bih[row] + bhh[row];

    if (l == 0) slot_store(&slots[row], h_init[row]);

    const int swz_w = ((tid >> 3) & 7) << 2;
    const int swz_r = (l & 7) << 2;

    float lastv = 0.f;
    long  gbudget = 1L << 21;

    for (int s = 0; s < TT; ++s) {
        // prefetch h0_{s+1} (independent of the poll; hides cache latency)
        const float* h0src = h0slots + (size_t)(s + 1) * HD + tid * 8;
        float4 p0 = *reinterpret_cast<const float4*>(h0src);
        float4 p1 = *reinterpret_cast<const float4*>(h0src + 4);

        float stash[8];
        poll8(slots + (size_t)s * HD + tid * 8, stash, gbudget);

        float* b1 = hb1[s & 1];
        float* b0 = hb0[s & 1];
        {
            const int base = tid * 8;
            float4 v0 = make_float4(stash[0], stash[1], stash[2], stash[3]);
            float4 v1 = make_float4(stash[4], stash[5], stash[6], stash[7]);
            *reinterpret_cast<float4*>(&b1[(base    ) ^ swz_w]) = v0;
            *reinterpret_cast<float4*>(&b1[(base + 4) ^ swz_w]) = v1;
            *reinterpret_cast<float4*>(&b0[(base    ) ^ swz_w]) = p0;
            *reinterpret_cast<float4*>(&b0[(base + 4) ^ swz_w]) = p1;
        }
        __syncthreads();

        float acc = 0.f;
        const int hbase = l * 64;
        #pragma unroll
        for (int q = 0; q < 16; ++q) {
            float4 h1v = *reinterpret_cast<const float4*>(&b1[(hbase + 4*q) ^ swz_r]);
            float4 h0v = *reinterpret_cast<const float4*>(&b0[(hbase + 4*q) ^ swz_r]);
            acc = fmaf(wh[4*q+0], h1v.x, acc);
            acc = fmaf(wh[4*q+1], h1v.y, acc);
            acc = fmaf(wh[4*q+2], h1v.z, acc);
            acc = fmaf(wh[4*q+3], h1v.w, acc);
            acc = fmaf(wi[4*q+0], h0v.x, acc);
            acc = fmaf(wi[4*q+1], h0v.y, acc);
            acc = fmaf(wi[4*q+2], h0v.z, acc);
            acc = fmaf(wi[4*q+3], h0v.w, acc);
        }
        #pragma unroll
        for (int m = 1; m < 32; m <<= 1) acc += __shfl_xor(acc, m);

        float val = tanhf(acc + bias);
        lastv = val;
        if (l == 0) slot_store(&slots[(size_t)(s + 1) * HD + row], val);
    }
    if (l == 0) outp[row] = lastv;
}

extern "C" void kernel_launch(void* const* d_in, const int* in_sizes, int n_in,
                              void* d_out, int out_size, void* d_ws, size_t ws_size,
                              hipStream_t stream)
{
    const float* x    = (const float*)d_in[0];
    const float* h    = (const float*)d_in[1];   // (2,1,H)
    const float* Wih0 = (const float*)d_in[2];
    const float* Whh0 = (const float*)d_in[3];
    const float* bih0 = (const float*)d_in[4];
    const float* bhh0 = (const float*)d_in[5];
    const float* Wih1 = (const float*)d_in[6];
    const float* Whh1 = (const float*)d_in[7];
    const float* bih1 = (const float*)d_in[8];
    const float* bhh1 = (const float*)d_in[9];
    float* out = (float*)d_out;

    float* slots0 = (float*)d_ws;
    float* slots1 = slots0 + (size_t)(TT + 1) * HD;
    size_t need = (size_t)2 * (TT + 1) * HD * sizeof(float);
    if (ws_size < need) return;   // would corrupt memory otherwise

    // sentinel-fill both slot regions (self-contained; don't rely on harness poison)
    hipMemsetAsync(d_ws, 0xAA, need, stream);

    hipLaunchKernelGGL(rnn_l0, dim3(NBLK), dim3(NTHR), 0, stream,
                       x, h, Wih0, Whh0, bih0, bhh0, slots0, out);
    hipLaunchKernelGGL(rnn_l1, dim3(NBLK), dim3(NTHR), 0, stream,
                       h + HD, Wih1, Whh1, bih1, bhh1, slots0, slots1, out + HD);
}

// Round 7
// 46697.952 us; speedup vs baseline: 1.8026x; 1.8026x over previous
//
#include <hip/hip_runtime.h>
#include <hip/hip_bf16.h>

#define HD 2048      // hidden size
#define TT 8192      // time steps
#define RPB 8        // rows per block
#define NTHR 256     // threads per block
#define SENTU 0xAAAAAAAAu

// Fused 2-layer Elman RNN as one 512-block pipelined kernel.
// Blocks [0,256): layer 0, rows 8b..8b+7.   h1_{s+1} = tanh(x[s]*wih0 + b + Whh0 h1_s)
// Blocks [256,512): layer 1, rows 8b'..     h2_{s+1} = tanh(Wih1 h1_{s+1} + b + Whh1 h2_s)
// Layer 1 trails layer 0 by one hop -> total span ~= TT hops, not 2*TT.
// Sync: data-flow polling on once-written slot words (sentinel 0xAAAAAAAA from
// our own memset), agent-scope atomics (coherence point = LLC, valid x-XCD).

__device__ __forceinline__ float fix_sent(float v) {
    return (__float_as_uint(v) == SENTU) ? __uint_as_float(0xAAAAAABAu) : v;
}
__device__ __forceinline__ void slot_store(float* p, float v) {
    __hip_atomic_store(p, fix_sent(v), __ATOMIC_RELAXED, __HIP_MEMORY_SCOPE_AGENT);
}
__device__ __forceinline__ unsigned long long slot_load64(const unsigned long long* p) {
    return __hip_atomic_load(p, __ATOMIC_RELAXED, __HIP_MEMORY_SCOPE_AGENT);
}

// Poll 4 64-bit pairs (8 floats). Valid when neither 32-bit half is sentinel.
// Doubly bounded: per-step pass cap + global budget -> fast wrong answer, no wedge.
// Adaptive: tight spin first 8 passes, then s_sleep(1) backoff.
__device__ __forceinline__ void poll8(const float* src, float* stash, long& gbudget) {
    const unsigned long long* p = reinterpret_cast<const unsigned long long*>(src);
    unsigned long long v[4];
    bool got[4] = {false, false, false, false};
    int passes = 1024;
    for (;;) {
        bool ok = true;
        #pragma unroll
        for (int j = 0; j < 4; ++j) if (!got[j]) {
            unsigned long long t = slot_load64(p + j);
            if ((unsigned)t != SENTU && (unsigned)(t >> 32) != SENTU) { v[j] = t; got[j] = true; }
            else ok = false;
        }
        if (ok) break;
        if (--passes < 0 || --gbudget < 0) {
            #pragma unroll
            for (int j = 0; j < 4; ++j) if (!got[j]) v[j] = 0ull;
            break;
        }
        if (passes < 1016) __builtin_amdgcn_s_sleep(1);
    }
    #pragma unroll
    for (int j = 0; j < 4; ++j) {
        stash[2*j]   = __uint_as_float((unsigned)v[j]);
        stash[2*j+1] = __uint_as_float((unsigned)(v[j] >> 32));
    }
}

// Combined poll of two 8-float regions (layer 1: own h + upstream h) in one loop
// so detection of both interleaves instead of serializing.
__device__ __forceinline__ void poll8x2(const float* srcA, const float* srcB,
                                        float* stA, float* stB, long& gbudget) {
    const unsigned long long* pA = reinterpret_cast<const unsigned long long*>(srcA);
    const unsigned long long* pB = reinterpret_cast<const unsigned long long*>(srcB);
    unsigned long long vA[4], vB[4];
    bool gA[4] = {false,false,false,false}, gB[4] = {false,false,false,false};
    int passes = 1024;
    for (;;) {
        bool ok = true;
        #pragma unroll
        for (int j = 0; j < 4; ++j) {
            if (!gA[j]) {
                unsigned long long t = slot_load64(pA + j);
                if ((unsigned)t != SENTU && (unsigned)(t >> 32) != SENTU) { vA[j] = t; gA[j] = true; }
                else ok = false;
            }
            if (!gB[j]) {
                unsigned long long t = slot_load64(pB + j);
                if ((unsigned)t != SENTU && (unsigned)(t >> 32) != SENTU) { vB[j] = t; gB[j] = true; }
                else ok = false;
            }
        }
        if (ok) break;
        if (--passes < 0 || --gbudget < 0) {
            #pragma unroll
            for (int j = 0; j < 4; ++j) { if (!gA[j]) vA[j] = 0ull; if (!gB[j]) vB[j] = 0ull; }
            break;
        }
        if (passes < 1016) __builtin_amdgcn_s_sleep(1);
    }
    #pragma unroll
    for (int j = 0; j < 4; ++j) {
        stA[2*j]   = __uint_as_float((unsigned)vA[j]);
        stA[2*j+1] = __uint_as_float((unsigned)(vA[j] >> 32));
        stB[2*j]   = __uint_as_float((unsigned)vB[j]);
        stB[2*j+1] = __uint_as_float((unsigned)(vB[j] >> 32));
    }
}

__global__ __launch_bounds__(NTHR, 2)   // 2 waves/EU -> 2 blocks/CU co-residency
void rnn_fused(const float* __restrict__ x,
               const float* __restrict__ h_init,    // (2,1,HD)
               const float* __restrict__ Wih0,      // (HD,1)
               const float* __restrict__ Whh0,      // (HD,HD)
               const float* __restrict__ bih0,
               const float* __restrict__ bhh0,
               const float* __restrict__ Wih1,      // (HD,HD)
               const float* __restrict__ Whh1,      // (HD,HD)
               const float* __restrict__ bih1,
               const float* __restrict__ bhh1,
               float* __restrict__ slots0,          // (TT+1) x HD
               float* __restrict__ slots1,          // (TT+1) x HD
               float* __restrict__ out)             // (2,1,HD) flat
{
    __shared__ float hbA[2][HD];   // l0: h1 stage | l1: h2 stage
    __shared__ float hbB[2][HD];   // l1 only: upstream h1 stage

    const int tid = threadIdx.x;
    const int bid = blockIdx.x;
    const bool l0 = (bid < 256);
    const int rb  = l0 ? bid : (bid - 256);
    const int r   = tid >> 5;
    const int l   = tid & 31;
    const int row = rb * RPB + r;

    // LDS xor-swizzle: word idx -> idx ^ (((idx>>6)&7)<<2). Breaks the 32-way
    // bank conflict of stride-64-word b128 reads down to 4-way. Swizzled
    // offsets stay 16B-aligned and < 2048 words.
    const int swz_w = ((tid >> 3) & 7) << 2;
    const int swz_r = (l & 7) << 2;

    float lastv = 0.f;
    long  gbudget = 1L << 21;   // worst-case total spin ~0.5 s -> fast wrong answer

    if (l0) {
        // ---- layer 0 ----
        float w[64];
        {
            const float4* wr = reinterpret_cast<const float4*>(Whh0 + (size_t)row * HD + l * 64);
            #pragma unroll
            for (int j = 0; j < 16; ++j) {
                float4 v = wr[j];
                w[4*j+0] = v.x; w[4*j+1] = v.y; w[4*j+2] = v.z; w[4*j+3] = v.w;
            }
        }
        const float wx   = Wih0[row];
        const float bias = bih0[row] + bhh0[row];

        if (l == 0) slot_store(&slots0[row], h_init[row]);

        for (int s = 0; s < TT; ++s) {
            float stash[8];
            poll8(slots0 + (size_t)s * HD + tid * 8, stash, gbudget);

            float* hbuf = hbA[s & 1];
            {
                const int base = tid * 8;
                float4 v0 = make_float4(stash[0], stash[1], stash[2], stash[3]);
                float4 v1 = make_float4(stash[4], stash[5], stash[6], stash[7]);
                *reinterpret_cast<float4*>(&hbuf[(base    ) ^ swz_w]) = v0;
                *reinterpret_cast<float4*>(&hbuf[(base + 4) ^ swz_w]) = v1;
            }
            __syncthreads();

            float acc = 0.f;
            const int hbase = l * 64;
            #pragma unroll
            for (int q = 0; q < 16; ++q) {
                float4 hv = *reinterpret_cast<const float4*>(&hbuf[(hbase + 4*q) ^ swz_r]);
                acc = fmaf(w[4*q+0], hv.x, acc);
                acc = fmaf(w[4*q+1], hv.y, acc);
                acc = fmaf(w[4*q+2], hv.z, acc);
                acc = fmaf(w[4*q+3], hv.w, acc);
            }
            #pragma unroll
            for (int m = 1; m < 32; m <<= 1) acc += __shfl_xor(acc, m);

            float val = tanhf(acc + bias + x[s] * wx);
            lastv = val;
            if (l == 0) slot_store(&slots0[(size_t)(s + 1) * HD + row], val);
        }
        if (l == 0) out[row] = lastv;
    } else {
        // ---- layer 1 (trails layer 0 by one hop) ----
        float wh[64], wi[64];
        {
            const float4* a = reinterpret_cast<const float4*>(Whh1 + (size_t)row * HD + l * 64);
            const float4* b = reinterpret_cast<const float4*>(Wih1 + (size_t)row * HD + l * 64);
            #pragma unroll
            for (int j = 0; j < 16; ++j) {
                float4 v = a[j];
                wh[4*j+0] = v.x; wh[4*j+1] = v.y; wh[4*j+2] = v.z; wh[4*j+3] = v.w;
                float4 u = b[j];
                wi[4*j+0] = u.x; wi[4*j+1] = u.y; wi[4*j+2] = u.z; wi[4*j+3] = u.w;
            }
        }
        const float bias = bih1[row] + bhh1[row];

        if (l == 0) slot_store(&slots1[row], h_init[HD + row]);

        for (int s = 0; s < TT; ++s) {
            float st1[8], st0[8];
            // needs own h2_s AND upstream h1_{s+1} (written by l0 at its step s)
            poll8x2(slots1 + (size_t)s * HD + tid * 8,
                    slots0 + (size_t)(s + 1) * HD + tid * 8,
                    st1, st0, gbudget);

            float* b1 = hbA[s & 1];
            float* b0 = hbB[s & 1];
            {
                const int base = tid * 8;
                *reinterpret_cast<float4*>(&b1[(base    ) ^ swz_w]) = make_float4(st1[0], st1[1], st1[2], st1[3]);
                *reinterpret_cast<float4*>(&b1[(base + 4) ^ swz_w]) = make_float4(st1[4], st1[5], st1[6], st1[7]);
                *reinterpret_cast<float4*>(&b0[(base    ) ^ swz_w]) = make_float4(st0[0], st0[1], st0[2], st0[3]);
                *reinterpret_cast<float4*>(&b0[(base + 4) ^ swz_w]) = make_float4(st0[4], st0[5], st0[6], st0[7]);
            }
            __syncthreads();

            float acc = 0.f;
            const int hbase = l * 64;
            #pragma unroll
            for (int q = 0; q < 16; ++q) {
                float4 h1v = *reinterpret_cast<const float4*>(&b1[(hbase + 4*q) ^ swz_r]);
                float4 h0v = *reinterpret_cast<const float4*>(&b0[(hbase + 4*q) ^ swz_r]);
                acc = fmaf(wh[4*q+0], h1v.x, acc);
                acc = fmaf(wh[4*q+1], h1v.y, acc);
                acc = fmaf(wh[4*q+2], h1v.z, acc);
                acc = fmaf(wh[4*q+3], h1v.w, acc);
                acc = fmaf(wi[4*q+0], h0v.x, acc);
                acc = fmaf(wi[4*q+1], h0v.y, acc);
                acc = fmaf(wi[4*q+2], h0v.z, acc);
                acc = fmaf(wi[4*q+3], h0v.w, acc);
            }
            #pragma unroll
            for (int m = 1; m < 32; m <<= 1) acc += __shfl_xor(acc, m);

            float val = tanhf(acc + bias);
            lastv = val;
            if (l == 0) slot_store(&slots1[(size_t)(s + 1) * HD + row], val);
        }
        if (l == 0) out[HD + row] = lastv;
    }
}

extern "C" void kernel_launch(void* const* d_in, const int* in_sizes, int n_in,
                              void* d_out, int out_size, void* d_ws, size_t ws_size,
                              hipStream_t stream)
{
    const float* x    = (const float*)d_in[0];
    const float* h    = (const float*)d_in[1];   // (2,1,H)
    const float* Wih0 = (const float*)d_in[2];
    const float* Whh0 = (const float*)d_in[3];
    const float* bih0 = (const float*)d_in[4];
    const float* bhh0 = (const float*)d_in[5];
    const float* Wih1 = (const float*)d_in[6];
    const float* Whh1 = (const float*)d_in[7];
    const float* bih1 = (const float*)d_in[8];
    const float* bhh1 = (const float*)d_in[9];
    float* out = (float*)d_out;

    float* slots0 = (float*)d_ws;
    float* slots1 = slots0 + (size_t)(TT + 1) * HD;
    size_t need = (size_t)2 * (TT + 1) * HD * sizeof(float);
    if (ws_size < need) return;

    // sentinel-fill both slot regions (self-contained; don't rely on harness poison)
    hipMemsetAsync(d_ws, 0xAA, need, stream);

    hipLaunchKernelGGL(rnn_fused, dim3(512), dim3(NTHR), 0, stream,
                       x, h, Wih0, Whh0, bih0, bhh0, Wih1, Whh1, bih1, bhh1,
                       slots0, slots1, out);
}

// Round 10
// 40590.207 us; speedup vs baseline: 2.0739x; 1.1505x over previous
//
#include <hip/hip_runtime.h>
#include <hip/hip_bf16.h>

#define HD 2048      // hidden size
#define TT 8192      // time steps
#define RPB 16       // rows per block
#define NTHR 512     // threads per block
#define SENTU 0xAAAAAAAAu

// Fused 2-layer Elman RNN, one 256-block pipelined kernel (1 block/CU).
// Blocks [0,128): layer 0.   h1_{s+1} = tanh(x[s]*wih0 + b + Whh0 h1_s)
// Blocks [128,256): layer 1. h2_{s+1} = tanh(Wih1 h1_{s+1} + b + Whh1 h2_s)
// Layer 1 trails layer 0 by one hop -> span ~= TT hops.
// Sync: dataflow polling on once-written slot PAIRS (8B atomics), sentinel
// 0xAAAAAAAA from our own memset. Producer packs 2 rows/wave via shfl_xor(32)
// into a single 8B store -> a block's 16 rows land as one 64B line.

typedef unsigned long long ull;

__device__ __forceinline__ unsigned fix_sent_u(float v) {
    unsigned u = __float_as_uint(v);
    return (u == SENTU) ? 0xAAAAAABAu : u;   // 2^-13 rel nudge on a 3e-13 value
}
__device__ __forceinline__ void slot_store_pair(ull* p, float lo, float hi) {
    ull v = (ull)fix_sent_u(lo) | ((ull)fix_sent_u(hi) << 32);
    __hip_atomic_store(p, v, __ATOMIC_RELAXED, __HIP_MEMORY_SCOPE_AGENT);
}
__device__ __forceinline__ ull slot_load64(const ull* p) {
    return __hip_atomic_load(p, __ATOMIC_RELAXED, __HIP_MEMORY_SCOPE_AGENT);
}
__device__ __forceinline__ bool pair_ok(ull t) {
    return ((unsigned)t != SENTU) && ((unsigned)(t >> 32) != SENTU);
}

// Poll 2 pairs (this thread's 4 h-words). Doubly bounded -> fast wrong answer,
// never a wedge. Tight-spin 8 passes, then s_sleep(1) backoff.
__device__ __forceinline__ void poll2(const ull* p, ull v[2], long& gb) {
    bool g0 = false, g1 = false;
    int passes = 1024;
    for (;;) {
        if (!g0) { ull t = slot_load64(p);     if (pair_ok(t)) { v[0] = t; g0 = true; } }
        if (!g1) { ull t = slot_load64(p + 1); if (pair_ok(t)) { v[1] = t; g1 = true; } }
        if (g0 && g1) return;
        if (--passes < 0 || --gb < 0) { if (!g0) v[0] = 0; if (!g1) v[1] = 0; return; }
        if (passes < 1016) __builtin_amdgcn_s_sleep(1);
    }
}
// Layer 1: poll own 2 pairs + upstream 2 pairs in one interleaved loop.
__device__ __forceinline__ void poll2x2(const ull* pA, const ull* pB,
                                        ull vA[2], ull vB[2], long& gb) {
    bool a0=false, a1=false, b0=false, b1=false;
    int passes = 1024;
    for (;;) {
        if (!a0) { ull t = slot_load64(pA);     if (pair_ok(t)) { vA[0] = t; a0 = true; } }
        if (!a1) { ull t = slot_load64(pA + 1); if (pair_ok(t)) { vA[1] = t; a1 = true; } }
        if (!b0) { ull t = slot_load64(pB);     if (pair_ok(t)) { vB[0] = t; b0 = true; } }
        if (!b1) { ull t = slot_load64(pB + 1); if (pair_ok(t)) { vB[1] = t; b1 = true; } }
        if (a0 && a1 && b0 && b1) return;
        if (--passes < 0 || --gb < 0) {
            if (!a0) vA[0] = 0; if (!a1) vA[1] = 0;
            if (!b0) vB[0] = 0; if (!b1) vB[1] = 0;
            return;
        }
        if (passes < 1016) __builtin_amdgcn_s_sleep(1);
    }
}
__device__ __forceinline__ float4 unpack4(ull v0, ull v1) {
    return make_float4(__uint_as_float((unsigned)v0),
                       __uint_as_float((unsigned)(v0 >> 32)),
                       __uint_as_float((unsigned)v1),
                       __uint_as_float((unsigned)(v1 >> 32)));
}

__global__ __launch_bounds__(NTHR, 2)   // 2 waves/EU -> 1 block/CU, 256 VGPR budget
void rnn_fused(const float* __restrict__ x,
               const float* __restrict__ h_init,    // (2,1,HD)
               const float* __restrict__ Wih0,      // (HD,1)
               const float* __restrict__ Whh0,      // (HD,HD)
               const float* __restrict__ bih0,
               const float* __restrict__ bhh0,
               const float* __restrict__ Wih1,      // (HD,HD)
               const float* __restrict__ Whh1,      // (HD,HD)
               const float* __restrict__ bih1,
               const float* __restrict__ bhh1,
               float* __restrict__ slots0,          // (TT+1) x HD
               float* __restrict__ slots1,          // (TT+1) x HD
               float* __restrict__ out)             // (2,1,HD) flat
{
    __shared__ float hbA[2][HD];   // l0: h1 stage | l1: h2 stage
    __shared__ float hbB[2][HD];   // l1 only: upstream h1 stage

    const int tid = threadIdx.x;
    const int bid = blockIdx.x;
    const bool is_l0 = (bid < 128);
    const int blk = is_l0 ? bid : (bid - 128);
    const int r   = tid >> 5;          // 0..15: row within block
    const int l   = tid & 31;          // col-group lane
    const int fl  = tid & 63;          // lane in physical wave
    const int wid = tid >> 6;          // physical wave 0..7 (owns rows 2w,2w+1)
    const int row = blk * RPB + r;

    // LDS xor-swizzle: word idx -> idx ^ (((idx>>6)&7)<<2). Breaks the 32-way
    // bank conflict of stride-64-word b128 reads down to 4-way; bijective.
    const int swz_w = ((tid >> 4) & 7) << 2;   // for write idx in [4tid, 4tid+4)
    const int swz_r = (l & 7) << 2;            // for read  idx in [l*64, l*64+64)

    // pair slot this wave publishes: rows {2*wid, 2*wid+1} of this block
    const size_t mypair_w = (size_t)blk * RPB + 2 * wid;   // word offset within a step

    float lastv = 0.f;
    long  gbudget = 1L << 21;   // worst-case total spin well under watchdog scale

    if (is_l0) {
        // ---- layer 0 ----
        float w[64];
        {
            const float4* wr = reinterpret_cast<const float4*>(Whh0 + (size_t)row * HD + l * 64);
            #pragma unroll
            for (int j = 0; j < 16; ++j) {
                float4 v = wr[j];
                w[4*j+0] = v.x; w[4*j+1] = v.y; w[4*j+2] = v.z; w[4*j+3] = v.w;
            }
        }
        const float wx   = Wih0[row];
        const float bias = bih0[row] + bhh0[row];

        { // publish initial h (slot 0) as pairs
            float v0 = h_init[row];
            float v1 = __shfl_xor(v0, 32);
            if (fl == 0)
                slot_store_pair(reinterpret_cast<ull*>(slots0 + mypair_w), v0, v1);
        }

        for (int s = 0; s < TT; ++s) {
            const float xv = x[s];
            ull pv[2];
            poll2(reinterpret_cast<const ull*>(slots0 + (size_t)s * HD + tid * 4), pv, gbudget);

            *reinterpret_cast<float4*>(&hbA[s & 1][(tid * 4) ^ swz_w]) = unpack4(pv[0], pv[1]);
            __syncthreads();

            const float* hbuf = hbA[s & 1];
            float acc = 0.f;
            const int hbase = l * 64;
            #pragma unroll
            for (int q = 0; q < 16; ++q) {
                float4 hv = *reinterpret_cast<const float4*>(&hbuf[(hbase + 4*q) ^ swz_r]);
                acc = fmaf(w[4*q+0], hv.x, acc);
                acc = fmaf(w[4*q+1], hv.y, acc);
                acc = fmaf(w[4*q+2], hv.z, acc);
                acc = fmaf(w[4*q+3], hv.w, acc);
            }
            #pragma unroll
            for (int m = 1; m < 32; m <<= 1) acc += __shfl_xor(acc, m);

            float val = tanhf(acc + bias + xv * wx);   // valid on ALL lanes (butterfly)
            lastv = val;
            float v1 = __shfl_xor(val, 32);            // partner row's value
            if (fl == 0)
                slot_store_pair(reinterpret_cast<ull*>(slots0 + (size_t)(s + 1) * HD + mypair_w),
                                val, v1);
        }
        if (l == 0) out[row] = lastv;   // lanes 0 and 32 cover rows 2w, 2w+1
    } else {
        // ---- layer 1 (trails layer 0 by one hop) ----
        float wh[64], wi[64];
        {
            const float4* a = reinterpret_cast<const float4*>(Whh1 + (size_t)row * HD + l * 64);
            const float4* b = reinterpret_cast<const float4*>(Wih1 + (size_t)row * HD + l * 64);
            #pragma unroll
            for (int j = 0; j < 16; ++j) {
                float4 v = a[j];
                wh[4*j+0] = v.x; wh[4*j+1] = v.y; wh[4*j+2] = v.z; wh[4*j+3] = v.w;
                float4 u = b[j];
                wi[4*j+0] = u.x; wi[4*j+1] = u.y; wi[4*j+2] = u.z; wi[4*j+3] = u.w;
            }
        }
        const float bias = bih1[row] + bhh1[row];

        { // publish initial h2 (slot 0)
            float v0 = h_init[HD + row];
            float v1 = __shfl_xor(v0, 32);
            if (fl == 0)
                slot_store_pair(reinterpret_cast<ull*>(slots1 + mypair_w), v0, v1);
        }

        for (int s = 0; s < TT; ++s) {
            ull p1[2], p0[2];
            // own h2_s AND upstream h1_{s+1} (written by l0 at its step s)
            poll2x2(reinterpret_cast<const ull*>(slots1 + (size_t)s * HD + tid * 4),
                    reinterpret_cast<const ull*>(slots0 + (size_t)(s + 1) * HD + tid * 4),
                    p1, p0, gbudget);

            *reinterpret_cast<float4*>(&hbA[s & 1][(tid * 4) ^ swz_w]) = unpack4(p1[0], p1[1]);
            *reinterpret_cast<float4*>(&hbB[s & 1][(tid * 4) ^ swz_w]) = unpack4(p0[0], p0[1]);
            __syncthreads();

            const float* b1 = hbA[s & 1];
            const float* b0 = hbB[s & 1];
            float acc = 0.f;
            const int hbase = l * 64;
            #pragma unroll
            for (int q = 0; q < 16; ++q) {
                float4 h1v = *reinterpret_cast<const float4*>(&b1[(hbase + 4*q) ^ swz_r]);
                float4 h0v = *reinterpret_cast<const float4*>(&b0[(hbase + 4*q) ^ swz_r]);
                acc = fmaf(wh[4*q+0], h1v.x, acc);
                acc = fmaf(wh[4*q+1], h1v.y, acc);
                acc = fmaf(wh[4*q+2], h1v.z, acc);
                acc = fmaf(wh[4*q+3], h1v.w, acc);
                acc = fmaf(wi[4*q+0], h0v.x, acc);
                acc = fmaf(wi[4*q+1], h0v.y, acc);
                acc = fmaf(wi[4*q+2], h0v.z, acc);
                acc = fmaf(wi[4*q+3], h0v.w, acc);
            }
            #pragma unroll
            for (int m = 1; m < 32; m <<= 1) acc += __shfl_xor(acc, m);

            float val = tanhf(acc + bias);
            lastv = val;
            float v1 = __shfl_xor(val, 32);
            if (fl == 0)
                slot_store_pair(reinterpret_cast<ull*>(slots1 + (size_t)(s + 1) * HD + mypair_w),
                                val, v1);
        }
        if (l == 0) out[HD + row] = lastv;
    }
}

extern "C" void kernel_launch(void* const* d_in, const int* in_sizes, int n_in,
                              void* d_out, int out_size, void* d_ws, size_t ws_size,
                              hipStream_t stream)
{
    const float* x    = (const float*)d_in[0];
    const float* h    = (const float*)d_in[1];   // (2,1,H)
    const float* Wih0 = (const float*)d_in[2];
    const float* Whh0 = (const float*)d_in[3];
    const float* bih0 = (const float*)d_in[4];
    const float* bhh0 = (const float*)d_in[5];
    const float* Wih1 = (const float*)d_in[6];
    const float* Whh1 = (const float*)d_in[7];
    const float* bih1 = (const float*)d_in[8];
    const float* bhh1 = (const float*)d_in[9];
    float* out = (float*)d_out;

    float* slots0 = (float*)d_ws;
    float* slots1 = slots0 + (size_t)(TT + 1) * HD;
    size_t need = (size_t)2 * (TT + 1) * HD * sizeof(float);
    if (ws_size < need) return;

    // sentinel-fill both slot regions (self-contained; don't rely on harness poison)
    hipMemsetAsync(d_ws, 0xAA, need, stream);

    hipLaunchKernelGGL(rnn_fused, dim3(256), dim3(NTHR), 0, stream,
                       x, h, Wih0, Whh0, bih0, bhh0, Wih1, Whh1, bih1, bhh1,
                       slots0, slots1, out);
}